// Round 6
// baseline (576.206 us; speedup 1.0000x reference)
//
#include <hip/hip_runtime.h>

#define NN 100000
#define NE 1600000
#define DF 32
#define DEPTH 10
#define LSTRIDE ((DEPTH + 1) * DF) /* 352 floats per node in d_out */
#define SCAN_BLOCKS 256
#define SCAN_T 256

// zero cnt (n ints) + cpack (cp4 int4s) in one fast kernel
__global__ void fill_k(int* __restrict__ cnt, int4* __restrict__ cpack4,
                       int n4_cnt, long long cp4) {
    long long i = (long long)blockIdx.x * blockDim.x + threadIdx.x;
    long long stride = (long long)gridDim.x * blockDim.x;
    const int4 z = make_int4(0, 0, 0, 0);
    for (long long j = i; j < cp4; j += stride) cpack4[j] = z;
    int4* c4 = (int4*)cnt;
    for (long long j = i; j < n4_cnt; j += stride) c4[j] = z;
}

// histogram + per-edge rank within its row (atomic result was free)
__global__ void hist_k(const int* __restrict__ row, int* __restrict__ cnt,
                       int* __restrict__ prank, int e) {
    int i = blockIdx.x * blockDim.x + threadIdx.x;
    int stride = gridDim.x * blockDim.x;
    for (; i < e; i += stride) {
        int r = __builtin_nontemporal_load(&row[i]);
        prank[i] = atomicAdd(&cnt[r], 1);
    }
}

// --- multi-block scan over PADDED counts ((cnt+7)&~7) ---
__global__ void scan_partial_k(const int* __restrict__ cnt, int* __restrict__ bsum,
                               int n, int chunk) {
    __shared__ int red[SCAN_T];
    int b = blockIdx.x, t = threadIdx.x;
    int beg = b * chunk, end = min(n, beg + chunk);
    int s = 0;
    for (int i = beg + t; i < end; i += SCAN_T) s += (cnt[i] + 7) & ~7;
    red[t] = s;
    __syncthreads();
    for (int off = SCAN_T / 2; off; off >>= 1) {
        if (t < off) red[t] += red[t + off];
        __syncthreads();
    }
    if (t == 0) bsum[b] = red[0];
}

__global__ void scan_bsum_k(const int* __restrict__ bsum, int* __restrict__ boff) {
    __shared__ int s[SCAN_BLOCKS];
    int t = threadIdx.x;
    s[t] = bsum[t];
    __syncthreads();
    for (int off = 1; off < SCAN_BLOCKS; off <<= 1) {
        int v = (t >= off) ? s[t - off] : 0;
        __syncthreads();
        s[t] += v;
        __syncthreads();
    }
    boff[t] = (t == 0) ? 0 : s[t - 1];
}

// emit padded-exclusive-prefix rowptr; also compute dinv from real cnt (fused).
__global__ void scan_emit_k(const int* __restrict__ cnt, const int* __restrict__ boff,
                            int* __restrict__ rowptr, float* __restrict__ dinv,
                            int n, int chunk) {
    __shared__ int tile[SCAN_T];
    int b = blockIdx.x, t = threadIdx.x;
    int beg = b * chunk, end = min(n, beg + chunk);
    int run = boff[b];
    for (int base = beg; base < end; base += SCAN_T) {
        int i = base + t;
        int creal = (i < end) ? cnt[i] : 0;
        int c = (creal + 7) & ~7;
        tile[t] = c;
        __syncthreads();
        for (int off = 1; off < SCAN_T; off <<= 1) {
            int v = (t >= off) ? tile[t - off] : 0;
            __syncthreads();
            tile[t] += v;
            __syncthreads();
        }
        if (i < end) {
            rowptr[i] = run + tile[t] - c; // exclusive prefix of padded counts
            float d = (creal == 0) ? 1.0f : (float)creal;
            dinv[i] = rsqrtf(d);
        }
        run += tile[SCAN_T - 1];
        __syncthreads();
    }
    if (b == gridDim.x - 1 && t == 0) rowptr[n] = run;
}

// atomic-free scatter: pos = rowptr[row] + prank (pad slots stay zero from fill_k)
__global__ void scatter_k(const int* __restrict__ row, const int* __restrict__ col,
                          const float* __restrict__ ea, const float* __restrict__ dinv,
                          const int* __restrict__ rowptr, const int* __restrict__ prank,
                          int2* __restrict__ cpack, int e) {
    int i = blockIdx.x * blockDim.x + threadIdx.x;
    int stride = gridDim.x * blockDim.x;
    for (; i < e; i += stride) {
        int r = __builtin_nontemporal_load(&row[i]);
        int c = __builtin_nontemporal_load(&col[i]);
        float a = __builtin_nontemporal_load(&ea[i]);
        int pr = __builtin_nontemporal_load(&prank[i]);
        float v = dinv[r] * a * dinv[c];
        int pos = rowptr[r] + pr;
        cpack[pos] = make_int2(c, __float_as_int(v));
    }
}

// out[node][0][:] = x[node][:]  (float4 vectorized)
__global__ void copy_k(const float* __restrict__ x, float* __restrict__ out, int n) {
    int t = blockIdx.x * blockDim.x + threadIdx.x; // n*8 float4s
    if (t < n * 8) {
        int node = t >> 3, q = t & 7;
        ((float4*)out)[(size_t)node * (LSTRIDE / 4) + q] = ((const float4*)x)[t];
    }
}

// persistent grid-stride; one 32-lane group per row per iteration; branch-free
// unroll-8 over padded CSR.
__global__ __launch_bounds__(256) void spmm_k(const int* __restrict__ rowptr,
                                              const unsigned long long* __restrict__ cpack,
                                              const float* __restrict__ pe,
                                              float* __restrict__ out, int n, int layer) {
    int lane = threadIdx.x & 31;
    int g0 = blockIdx.x * 8 + (threadIdx.x >> 5);
    int gstride = gridDim.x * 8;
    float alpha = tanhf(pe[layer]); // BASE_ALPHA = 1
    const float* __restrict__ hsrc = out + (size_t)layer * DF + lane;
    for (int gid = g0; gid < n; gid += gstride) {
        int beg = rowptr[gid], end = rowptr[gid + 1]; // multiple of 8 apart
        float acc = 0.f;
        for (int base = beg; base < end; base += 8) {
            unsigned long long p[8];
#pragma unroll
            for (int u = 0; u < 8; ++u) p[u] = __builtin_nontemporal_load(&cpack[base + u]);
            float h[8];
#pragma unroll
            for (int u = 0; u < 8; ++u)
                h[u] = hsrc[(unsigned)(p[u] & 0xFFFFFFFFu) * (unsigned)LSTRIDE];
#pragma unroll
            for (int u = 0; u < 8; ++u)
                acc = fmaf(__uint_as_float((unsigned)(p[u] >> 32)), h[u], acc);
        }
        out[(size_t)gid * LSTRIDE + (layer + 1) * DF + lane] = alpha * acc;
    }
}

extern "C" void kernel_launch(void* const* d_in, const int* in_sizes, int n_in,
                              void* d_out, int out_size, void* d_ws, size_t ws_size,
                              hipStream_t stream) {
    const float* x  = (const float*)d_in[0];
    const int*   ei = (const int*)d_in[1];
    const float* ea = (const float*)d_in[2];
    const float* pe = (const float*)d_in[3];
    float* out = (float*)d_out;

    const int n = in_sizes[0] / DF;   // 100000
    const int e = in_sizes[2];        // 1600000
    const int* row = ei;
    const int* col = ei + e;

    // workspace layout
    int*   cnt    = (int*)d_ws;               // n  (16B-aligned: ws base)
    int*   rowptr = cnt + n;                  // n+1
    float* dinv   = (float*)(rowptr + n + 1); // n
    int*   bsum   = (int*)(dinv + n);         // SCAN_BLOCKS
    int*   boff   = bsum + SCAN_BLOCKS;       // SCAN_BLOCKS
    int*   prank  = boff + SCAN_BLOCKS;       // e
    size_t off = ((size_t)(prank + e) - (size_t)d_ws + 15) & ~(size_t)15;
    int2*  cpack = (int2*)((char*)d_ws + off); // up to e + 7n entries (padded CSR)

    const long long cpack_entries = (long long)e + 7ll * n;
    const long long cp4 = (cpack_entries * 2 + 3) / 4; // int4 count covering cpack
    const int n4_cnt = (n + 3) / 4;

    const int chunk = (n + SCAN_BLOCKS - 1) / SCAN_BLOCKS;

    fill_k<<<2048, 256, 0, stream>>>(cnt, (int4*)cpack, n4_cnt, cp4);
    hist_k<<<2048, 256, 0, stream>>>(row, cnt, prank, e);
    scan_partial_k<<<SCAN_BLOCKS, SCAN_T, 0, stream>>>(cnt, bsum, n, chunk);
    scan_bsum_k<<<1, SCAN_BLOCKS, 0, stream>>>(bsum, boff);
    scan_emit_k<<<SCAN_BLOCKS, SCAN_T, 0, stream>>>(cnt, boff, rowptr, dinv, n, chunk);
    scatter_k<<<2048, 256, 0, stream>>>(row, col, ea, dinv, rowptr, prank, cpack, e);
    copy_k<<<(n * 8 + 255) / 256, 256, 0, stream>>>(x, out, n);

    for (int L = 0; L < DEPTH; ++L) {
        spmm_k<<<2048, 256, 0, stream>>>(rowptr, (const unsigned long long*)cpack,
                                         pe, out, n, L);
    }
}

// Round 7
// 567.119 us; speedup vs baseline: 1.0160x; 1.0160x over previous
//
#include <hip/hip_runtime.h>

#define NN 100000
#define NE 1600000
#define DF 32
#define DEPTH 10
#define LSTRIDE ((DEPTH + 1) * DF) /* 352 floats per node in d_out */
#define SCAN_BLOCKS 256
#define SCAN_T 256

// zero cnt (n ints) + cpack (cp4 int4s) in one fast kernel
__global__ void fill_k(int* __restrict__ cnt, int4* __restrict__ cpack4,
                       int n4_cnt, long long cp4) {
    long long i = (long long)blockIdx.x * blockDim.x + threadIdx.x;
    long long stride = (long long)gridDim.x * blockDim.x;
    const int4 z = make_int4(0, 0, 0, 0);
    for (long long j = i; j < cp4; j += stride) cpack4[j] = z;
    int4* c4 = (int4*)cnt;
    for (long long j = i; j < n4_cnt; j += stride) c4[j] = z;
}

// histogram + per-edge rank within its row (atomic result was free)
__global__ void hist_k(const int* __restrict__ row, int* __restrict__ cnt,
                       int* __restrict__ prank, int e) {
    int i = blockIdx.x * blockDim.x + threadIdx.x;
    int stride = gridDim.x * blockDim.x;
    for (; i < e; i += stride) {
        int r = __builtin_nontemporal_load(&row[i]);
        prank[i] = atomicAdd(&cnt[r], 1);
    }
}

// --- multi-block scan over PADDED counts ((cnt+7)&~7) ---
__global__ void scan_partial_k(const int* __restrict__ cnt, int* __restrict__ bsum,
                               int n, int chunk) {
    __shared__ int red[SCAN_T];
    int b = blockIdx.x, t = threadIdx.x;
    int beg = b * chunk, end = min(n, beg + chunk);
    int s = 0;
    for (int i = beg + t; i < end; i += SCAN_T) s += (cnt[i] + 7) & ~7;
    red[t] = s;
    __syncthreads();
    for (int off = SCAN_T / 2; off; off >>= 1) {
        if (t < off) red[t] += red[t + off];
        __syncthreads();
    }
    if (t == 0) bsum[b] = red[0];
}

__global__ void scan_bsum_k(const int* __restrict__ bsum, int* __restrict__ boff) {
    __shared__ int s[SCAN_BLOCKS];
    int t = threadIdx.x;
    s[t] = bsum[t];
    __syncthreads();
    for (int off = 1; off < SCAN_BLOCKS; off <<= 1) {
        int v = (t >= off) ? s[t - off] : 0;
        __syncthreads();
        s[t] += v;
        __syncthreads();
    }
    boff[t] = (t == 0) ? 0 : s[t - 1];
}

// emit padded-exclusive-prefix rowptr; also compute dinv from real cnt (fused).
__global__ void scan_emit_k(const int* __restrict__ cnt, const int* __restrict__ boff,
                            int* __restrict__ rowptr, float* __restrict__ dinv,
                            int n, int chunk) {
    __shared__ int tile[SCAN_T];
    int b = blockIdx.x, t = threadIdx.x;
    int beg = b * chunk, end = min(n, beg + chunk);
    int run = boff[b];
    for (int base = beg; base < end; base += SCAN_T) {
        int i = base + t;
        int creal = (i < end) ? cnt[i] : 0;
        int c = (creal + 7) & ~7;
        tile[t] = c;
        __syncthreads();
        for (int off = 1; off < SCAN_T; off <<= 1) {
            int v = (t >= off) ? tile[t - off] : 0;
            __syncthreads();
            tile[t] += v;
            __syncthreads();
        }
        if (i < end) {
            rowptr[i] = run + tile[t] - c; // exclusive prefix of padded counts
            float d = (creal == 0) ? 1.0f : (float)creal;
            dinv[i] = rsqrtf(d);
        }
        run += tile[SCAN_T - 1];
        __syncthreads();
    }
    if (b == gridDim.x - 1 && t == 0) rowptr[n] = run;
}

// atomic-free scatter: pos = rowptr[row] + prank (pad slots stay zero from fill_k)
__global__ void scatter_k(const int* __restrict__ row, const int* __restrict__ col,
                          const float* __restrict__ ea, const float* __restrict__ dinv,
                          const int* __restrict__ rowptr, const int* __restrict__ prank,
                          int2* __restrict__ cpack, int e) {
    int i = blockIdx.x * blockDim.x + threadIdx.x;
    int stride = gridDim.x * blockDim.x;
    for (; i < e; i += stride) {
        int r = __builtin_nontemporal_load(&row[i]);
        int c = __builtin_nontemporal_load(&col[i]);
        float a = __builtin_nontemporal_load(&ea[i]);
        int pr = __builtin_nontemporal_load(&prank[i]);
        float v = dinv[r] * a * dinv[c];
        int pos = rowptr[r] + pr;
        cpack[pos] = make_int2(c, __float_as_int(v));
    }
}

__device__ __forceinline__ unsigned short f32_to_bf16(float f) {
    unsigned b = __float_as_uint(f);
    b += 0x7FFFu + ((b >> 16) & 1u); // round-to-nearest-even
    return (unsigned short)(b >> 16);
}

// out[node][0][:] = x[node][:] (float4) and hb0[node][:] = bf16(x)
__global__ void copy_k(const float* __restrict__ x, float* __restrict__ out,
                       unsigned short* __restrict__ hb0, int n) {
    int t = blockIdx.x * blockDim.x + threadIdx.x; // n*8 float4s
    if (t < n * 8) {
        int node = t >> 3, q = t & 7;
        float4 v = ((const float4*)x)[t];
        ((float4*)out)[(size_t)node * (LSTRIDE / 4) + q] = v;
        ushort4 h;
        h.x = f32_to_bf16(v.x); h.y = f32_to_bf16(v.y);
        h.z = f32_to_bf16(v.z); h.w = f32_to_bf16(v.w);
        ((ushort4*)hb0)[t] = h;
    }
}

// one 32-lane group per row; lane = feature; branch-free unroll-8 over padded CSR.
// Gathers bf16 h (64B/edge), accumulates f32, writes f32 to out + bf16 to next ping.
__global__ __launch_bounds__(256) void spmm_k(const int* __restrict__ rowptr,
                                              const unsigned long long* __restrict__ cpack,
                                              const float* __restrict__ pe,
                                              const unsigned short* __restrict__ hin,
                                              unsigned short* __restrict__ hout,
                                              float* __restrict__ out, int n, int layer) {
    int gid = blockIdx.x * 8 + (threadIdx.x >> 5);
    int lane = threadIdx.x & 31;
    if (gid >= n) return;
    float alpha = tanhf(pe[layer]); // BASE_ALPHA = 1
    const unsigned short* __restrict__ hsrc = hin + lane;
    int beg = rowptr[gid], end = rowptr[gid + 1]; // multiple of 8 apart
    float acc = 0.f;
    for (int base = beg; base < end; base += 8) {
        unsigned long long p[8];
#pragma unroll
        for (int u = 0; u < 8; ++u) p[u] = __builtin_nontemporal_load(&cpack[base + u]);
        unsigned short h[8];
#pragma unroll
        for (int u = 0; u < 8; ++u)
            h[u] = hsrc[(unsigned)(p[u] & 0xFFFFFFFFu) * (unsigned)DF];
#pragma unroll
        for (int u = 0; u < 8; ++u)
            acc = fmaf(__uint_as_float((unsigned)(p[u] >> 32)),
                       __uint_as_float((unsigned)h[u] << 16), acc);
    }
    float r = alpha * acc;
    out[(size_t)gid * LSTRIDE + (layer + 1) * DF + lane] = r;
    hout[(unsigned)gid * DF + lane] = f32_to_bf16(r);
}

extern "C" void kernel_launch(void* const* d_in, const int* in_sizes, int n_in,
                              void* d_out, int out_size, void* d_ws, size_t ws_size,
                              hipStream_t stream) {
    const float* x  = (const float*)d_in[0];
    const int*   ei = (const int*)d_in[1];
    const float* ea = (const float*)d_in[2];
    const float* pe = (const float*)d_in[3];
    float* out = (float*)d_out;

    const int n = in_sizes[0] / DF;   // 100000
    const int e = in_sizes[2];        // 1600000
    const int* row = ei;
    const int* col = ei + e;

    // workspace layout
    int*   cnt    = (int*)d_ws;               // n  (16B-aligned: ws base)
    int*   rowptr = cnt + n;                  // n+1
    float* dinv   = (float*)(rowptr + n + 1); // n
    int*   bsum   = (int*)(dinv + n);         // SCAN_BLOCKS
    int*   boff   = bsum + SCAN_BLOCKS;       // SCAN_BLOCKS
    int*   prank  = boff + SCAN_BLOCKS;       // e
    size_t off = ((size_t)(prank + e) - (size_t)d_ws + 15) & ~(size_t)15;
    int2*  cpack = (int2*)((char*)d_ws + off); // e + 7n entries (padded CSR)
    const long long cpack_entries = (long long)e + 7ll * n;
    unsigned short* hb0 = (unsigned short*)(cpack + cpack_entries); // n*DF bf16
    unsigned short* hb1 = hb0 + (size_t)n * DF;                     // n*DF bf16

    const long long cp4 = (cpack_entries * 2 + 3) / 4; // int4 count covering cpack
    const int n4_cnt = (n + 3) / 4;

    const int chunk = (n + SCAN_BLOCKS - 1) / SCAN_BLOCKS;

    fill_k<<<2048, 256, 0, stream>>>(cnt, (int4*)cpack, n4_cnt, cp4);
    hist_k<<<2048, 256, 0, stream>>>(row, cnt, prank, e);
    scan_partial_k<<<SCAN_BLOCKS, SCAN_T, 0, stream>>>(cnt, bsum, n, chunk);
    scan_bsum_k<<<1, SCAN_BLOCKS, 0, stream>>>(bsum, boff);
    scan_emit_k<<<SCAN_BLOCKS, SCAN_T, 0, stream>>>(cnt, boff, rowptr, dinv, n, chunk);
    scatter_k<<<2048, 256, 0, stream>>>(row, col, ea, dinv, rowptr, prank, cpack, e);
    copy_k<<<(n * 8 + 255) / 256, 256, 0, stream>>>(x, out, hb0, n);

    for (int L = 0; L < DEPTH; ++L) {
        unsigned short* hin  = (L & 1) ? hb1 : hb0;
        unsigned short* hout = (L & 1) ? hb0 : hb1;
        spmm_k<<<(n + 7) / 8, 256, 0, stream>>>(rowptr, (const unsigned long long*)cpack,
                                                pe, hin, hout, out, n, L);
    }
}

// Round 9
// 529.488 us; speedup vs baseline: 1.0882x; 1.0711x over previous
//
#include <hip/hip_runtime.h>

#define NN 100000
#define NE 1600000
#define DF 32
#define DEPTH 10
#define LSTRIDE ((DEPTH + 1) * DF) /* 352 floats per node in d_out */
#define SCAN_BLOCKS 256
#define SCAN_T 256

// zero cnt (n ints) + cpack (cp4 int4s) in one fast kernel
__global__ void fill_k(int* __restrict__ cnt, int4* __restrict__ cpack4,
                       int n4_cnt, long long cp4) {
    long long i = (long long)blockIdx.x * blockDim.x + threadIdx.x;
    long long stride = (long long)gridDim.x * blockDim.x;
    const int4 z = make_int4(0, 0, 0, 0);
    for (long long j = i; j < cp4; j += stride) cpack4[j] = z;
    int4* c4 = (int4*)cnt;
    for (long long j = i; j < n4_cnt; j += stride) c4[j] = z;
}

// histogram + per-edge rank within its row (atomic result was free)
__global__ void hist_k(const int* __restrict__ row, int* __restrict__ cnt,
                       int* __restrict__ prank, int e) {
    int i = blockIdx.x * blockDim.x + threadIdx.x;
    int stride = gridDim.x * blockDim.x;
    for (; i < e; i += stride) {
        int r = __builtin_nontemporal_load(&row[i]);
        prank[i] = atomicAdd(&cnt[r], 1);
    }
}

// --- multi-block scan over PADDED counts ((cnt+7)&~7) ---
__global__ void scan_partial_k(const int* __restrict__ cnt, int* __restrict__ bsum,
                               int n, int chunk) {
    __shared__ int red[SCAN_T];
    int b = blockIdx.x, t = threadIdx.x;
    int beg = b * chunk, end = min(n, beg + chunk);
    int s = 0;
    for (int i = beg + t; i < end; i += SCAN_T) s += (cnt[i] + 7) & ~7;
    red[t] = s;
    __syncthreads();
    for (int off = SCAN_T / 2; off; off >>= 1) {
        if (t < off) red[t] += red[t + off];
        __syncthreads();
    }
    if (t == 0) bsum[b] = red[0];
}

__global__ void scan_bsum_k(const int* __restrict__ bsum, int* __restrict__ boff) {
    __shared__ int s[SCAN_BLOCKS];
    int t = threadIdx.x;
    s[t] = bsum[t];
    __syncthreads();
    for (int off = 1; off < SCAN_BLOCKS; off <<= 1) {
        int v = (t >= off) ? s[t - off] : 0;
        __syncthreads();
        s[t] += v;
        __syncthreads();
    }
    boff[t] = (t == 0) ? 0 : s[t - 1];
}

// emit padded-exclusive-prefix rowptr; also compute dinv from real cnt (fused).
__global__ void scan_emit_k(const int* __restrict__ cnt, const int* __restrict__ boff,
                            int* __restrict__ rowptr, float* __restrict__ dinv,
                            int n, int chunk) {
    __shared__ int tile[SCAN_T];
    int b = blockIdx.x, t = threadIdx.x;
    int beg = b * chunk, end = min(n, beg + chunk);
    int run = boff[b];
    for (int base = beg; base < end; base += SCAN_T) {
        int i = base + t;
        int creal = (i < end) ? cnt[i] : 0;
        int c = (creal + 7) & ~7;
        tile[t] = c;
        __syncthreads();
        for (int off = 1; off < SCAN_T; off <<= 1) {
            int v = (t >= off) ? tile[t - off] : 0;
            __syncthreads();
            tile[t] += v;
            __syncthreads();
        }
        if (i < end) {
            rowptr[i] = run + tile[t] - c; // exclusive prefix of padded counts
            float d = (creal == 0) ? 1.0f : (float)creal;
            dinv[i] = rsqrtf(d);
        }
        run += tile[SCAN_T - 1];
        __syncthreads();
    }
    if (b == gridDim.x - 1 && t == 0) rowptr[n] = run;
}

// atomic-free scatter: pos = rowptr[row] + prank (pad slots stay zero from fill_k).
// NT store (packed u64 — vector types rejected by the builtin): bypass per-XCD L2
// so the 8 sub-writes of each 64B line merge in the shared memory-side cache.
__global__ void scatter_k(const int* __restrict__ row, const int* __restrict__ col,
                          const float* __restrict__ ea, const float* __restrict__ dinv,
                          const int* __restrict__ rowptr, const int* __restrict__ prank,
                          unsigned long long* __restrict__ cpack, int e) {
    int i = blockIdx.x * blockDim.x + threadIdx.x;
    int stride = gridDim.x * blockDim.x;
    for (; i < e; i += stride) {
        int r = __builtin_nontemporal_load(&row[i]);
        int c = __builtin_nontemporal_load(&col[i]);
        float a = __builtin_nontemporal_load(&ea[i]);
        int pr = __builtin_nontemporal_load(&prank[i]);
        float v = dinv[r] * a * dinv[c];
        int pos = rowptr[r] + pr;
        unsigned long long pk =
            ((unsigned long long)(unsigned)__float_as_int(v) << 32) | (unsigned)c;
        __builtin_nontemporal_store(pk, &cpack[pos]);
    }
}

// out[node][0][:] = x[node][:]  (float4 vectorized)
__global__ void copy_k(const float* __restrict__ x, float* __restrict__ out, int n) {
    int t = blockIdx.x * blockDim.x + threadIdx.x; // n*8 float4s
    if (t < n * 8) {
        int node = t >> 3, q = t & 7;
        ((float4*)out)[(size_t)node * (LSTRIDE / 4) + q] = ((const float4*)x)[t];
    }
}

// one 32-lane group per row; lane = feature; branch-free unroll-8 over padded CSR.
__global__ __launch_bounds__(256) void spmm_k(const int* __restrict__ rowptr,
                                              const unsigned long long* __restrict__ cpack,
                                              const float* __restrict__ pe,
                                              float* __restrict__ out, int n, int layer) {
    int gid = blockIdx.x * 8 + (threadIdx.x >> 5);
    int lane = threadIdx.x & 31;
    if (gid >= n) return;
    float alpha = tanhf(pe[layer]); // BASE_ALPHA = 1
    const float* __restrict__ hsrc = out + (size_t)layer * DF + lane;
    int beg = rowptr[gid], end = rowptr[gid + 1]; // multiple of 8 apart
    float acc = 0.f;
    for (int base = beg; base < end; base += 8) {
        unsigned long long p[8];
#pragma unroll
        for (int u = 0; u < 8; ++u) p[u] = __builtin_nontemporal_load(&cpack[base + u]);
        float h[8];
#pragma unroll
        for (int u = 0; u < 8; ++u)
            h[u] = hsrc[(unsigned)(p[u] & 0xFFFFFFFFu) * (unsigned)LSTRIDE];
#pragma unroll
        for (int u = 0; u < 8; ++u)
            acc = fmaf(__uint_as_float((unsigned)(p[u] >> 32)), h[u], acc);
    }
    out[(size_t)gid * LSTRIDE + (layer + 1) * DF + lane] = alpha * acc;
}

extern "C" void kernel_launch(void* const* d_in, const int* in_sizes, int n_in,
                              void* d_out, int out_size, void* d_ws, size_t ws_size,
                              hipStream_t stream) {
    const float* x  = (const float*)d_in[0];
    const int*   ei = (const int*)d_in[1];
    const float* ea = (const float*)d_in[2];
    const float* pe = (const float*)d_in[3];
    float* out = (float*)d_out;

    const int n = in_sizes[0] / DF;   // 100000
    const int e = in_sizes[2];        // 1600000
    const int* row = ei;
    const int* col = ei + e;

    // workspace layout
    int*   cnt    = (int*)d_ws;               // n  (16B-aligned: ws base)
    int*   rowptr = cnt + n;                  // n+1
    float* dinv   = (float*)(rowptr + n + 1); // n
    int*   bsum   = (int*)(dinv + n);         // SCAN_BLOCKS
    int*   boff   = bsum + SCAN_BLOCKS;       // SCAN_BLOCKS
    int*   prank  = boff + SCAN_BLOCKS;       // e
    size_t off = ((size_t)(prank + e) - (size_t)d_ws + 15) & ~(size_t)15;
    unsigned long long* cpack = (unsigned long long*)((char*)d_ws + off); // e + 7n entries

    const long long cpack_entries = (long long)e + 7ll * n;
    const long long cp4 = (cpack_entries * 2 + 3) / 4; // int4 count covering cpack
    const int n4_cnt = (n + 3) / 4;

    const int chunk = (n + SCAN_BLOCKS - 1) / SCAN_BLOCKS;

    fill_k<<<2048, 256, 0, stream>>>(cnt, (int4*)cpack, n4_cnt, cp4);
    hist_k<<<2048, 256, 0, stream>>>(row, cnt, prank, e);
    scan_partial_k<<<SCAN_BLOCKS, SCAN_T, 0, stream>>>(cnt, bsum, n, chunk);
    scan_bsum_k<<<1, SCAN_BLOCKS, 0, stream>>>(bsum, boff);
    scan_emit_k<<<SCAN_BLOCKS, SCAN_T, 0, stream>>>(cnt, boff, rowptr, dinv, n, chunk);
    scatter_k<<<2048, 256, 0, stream>>>(row, col, ea, dinv, rowptr, prank, cpack, e);
    copy_k<<<(n * 8 + 255) / 256, 256, 0, stream>>>(x, out, n);

    for (int L = 0; L < DEPTH; ++L) {
        spmm_k<<<(n + 7) / 8, 256, 0, stream>>>(rowptr, cpack, pe, out, n, L);
    }
}